// Round 1
// baseline (33676.007 us; speedup 1.0000x reference)
//
#include <hip/hip_runtime.h>

#define T_STEPS 1024
#define BATCH   128
#define HID     128
#define GATES   512   // 4*HID
#define KDIM    256   // [x | h]
#define STACK   1024

__device__ __forceinline__ float sigf(float x) {
    return 1.0f / (1.0f + __expf(-x));
}
__device__ __forceinline__ float tanhfast(float x) {
    // tanh(x) = 1 - 2/(exp(2x)+1); saturates correctly at +/-inf
    return 1.0f - 2.0f / (1.0f + __expf(2.0f * x));
}

// dot of 256 private weights against a wave-uniform LDS vector (broadcast reads)
__device__ __forceinline__ float dot256(const float* __restrict__ w, const float* v) {
    float a0 = 0.f, a1 = 0.f, a2 = 0.f, a3 = 0.f;
#pragma unroll
    for (int k = 0; k < KDIM / 4; ++k) {
        float4 x4 = reinterpret_cast<const float4*>(v)[k];
        a0 = fmaf(w[4 * k + 0], x4.x, a0);
        a1 = fmaf(w[4 * k + 1], x4.y, a1);
        a2 = fmaf(w[4 * k + 2], x4.z, a2);
        a3 = fmaf(w[4 * k + 3], x4.w, a3);
    }
    return (a0 + a1) + (a2 + a3);
}

__launch_bounds__(1024, 1)
__global__ void stack_lstm_kernel(const float* __restrict__ inputs,
                                  const int*   __restrict__ ops,
                                  const float* __restrict__ w_ih,
                                  const float* __restrict__ w_hh,
                                  const float* __restrict__ b_ih,
                                  const float* __restrict__ b_hh,
                                  float* __restrict__ out)
{
    const int r   = blockIdx.x;   // batch row
    const int tid = threadIdx.x;  // 0..1023

    // LDS: double-buffered [x_t | h0_cur], single-buffered [h0_new | h1_cur], gate scratch
    __shared__ __align__(16) float xh0[2][KDIM];
    __shared__ __align__(16) float xh1[KDIM];
    __shared__ __align__(16) float g0[GATES];
    __shared__ __align__(16) float g1[GATES];

    const int layer = (tid < 512) ? 0 : 1;  // waves 0-7: layer0 rows, waves 8-15: layer1 rows
    const int o     = tid & 511;            // gate-row index within the layer

    // Persistent per-lane weights: one gate row, [W_ih | W_hh] = 256 fp32 in VGPRs
    float w[KDIM];
    {
        const float* Wi = w_ih + (size_t)(layer * GATES + o) * HID;
        const float* Wh = w_hh + (size_t)(layer * GATES + o) * HID;
#pragma unroll
        for (int k = 0; k < HID / 4; ++k) {
            float4 a = reinterpret_cast<const float4*>(Wi)[k];
            w[4 * k + 0] = a.x; w[4 * k + 1] = a.y;
            w[4 * k + 2] = a.z; w[4 * k + 3] = a.w;
            float4 b = reinterpret_cast<const float4*>(Wh)[k];
            w[HID + 4 * k + 0] = b.x; w[HID + 4 * k + 1] = b.y;
            w[HID + 4 * k + 2] = b.z; w[HID + 4 * k + 3] = b.w;
        }
    }
    const float bias = b_ih[layer * GATES + o] + b_hh[layer * GATES + o];

    // init state
    if (tid < HID) {
        xh0[0][HID + tid] = 0.f;   // h0 at stack slot 0
        xh0[1][HID + tid] = 0.f;
        xh1[HID + tid]    = 0.f;   // h1 at stack slot 0
        xh0[0][tid] = inputs[(size_t)r * HID + tid];  // x_0
    }
    float c_cur = 0.f;  // lanes [0,128): c0[j];  lanes [512,640): c1[j]
    int   pos   = 0;    // tracked by lanes [512,640)
    __syncthreads();

    for (int t = 0; t < T_STEPS; ++t) {
        const int buf = t & 1;

        // ---- S0: layer-0 matvec (waves 0-7); x(t+1) prefetch (wave 8-9 lanes) ----
        if (tid < 512) {
            g0[o] = dot256(w, xh0[buf]) + bias;
        } else if (tid < 512 + HID) {
            if (t + 1 < T_STEPS)
                xh0[buf ^ 1][tid - 512] =
                    inputs[(size_t)(t + 1) * BATCH * HID + (size_t)r * HID + (tid - 512)];
        }
        __syncthreads();

        // ---- S1: layer-0 epilogue (lanes 0..127) ----
        if (tid < HID) {
            const int op = ops[t * BATCH + r];
            const float gi = g0[tid];
            const float gf = g0[HID + tid];
            const float gg = g0[2 * HID + tid];
            const float go = g0[3 * HID + tid];
            const float c_new = sigf(gf) * c_cur + sigf(gi) * tanhfast(gg);
            const float h_new = sigf(go) * tanhfast(c_new);
            xh1[tid] = h_new;                          // layer-1 input (every step)
            const float h_old = xh0[buf][HID + tid];
            xh0[buf ^ 1][HID + tid] = op ? h_new : h_old;  // frozen stack-top h0
            c_cur = op ? c_new : c_cur;                    // frozen stack-top c0
        }
        __syncthreads();

        // ---- S2: layer-1 matvec (waves 8-15) ----
        if (tid >= 512) {
            g1[o] = dot256(w, xh1) + bias;
        }
        __syncthreads();

        // ---- S3: layer-1 epilogue + output stream (lanes 512..639) ----
        if (tid >= 512 && tid < 512 + HID) {
            const int j  = tid - 512;
            const int op = ops[t * BATCH + r];
            const float gi = g1[j];
            const float gf = g1[HID + j];
            const float gg = g1[2 * HID + j];
            const float go = g1[3 * HID + j];
            const float c_new = sigf(gf) * c_cur + sigf(gi) * tanhfast(gg);
            const float h_new = sigf(go) * tanhfast(c_new);
            // contents[pos+1, r, j] — later writes to same slot legally overwrite
            out[(size_t)(pos + 1) * BATCH * HID + (size_t)r * HID + j] = h_new;
            const float h_old = xh1[HID + j];
            xh1[HID + j] = op ? h_new : h_old;  // frozen stack-top h1
            c_cur = op ? c_new : c_cur;         // frozen stack-top c1
            pos += op;
        }
        __syncthreads();
    }

    // final pos (as float32 — exact for integers <= 1024)
    if (tid == 512) {
        out[(size_t)(STACK + 1) * BATCH * HID + r] = (float)pos;
    }
}

extern "C" void kernel_launch(void* const* d_in, const int* in_sizes, int n_in,
                              void* d_out, int out_size, void* d_ws, size_t ws_size,
                              hipStream_t stream)
{
    (void)in_sizes; (void)n_in; (void)d_ws; (void)ws_size;
    const float* inputs = (const float*)d_in[0];
    const int*   ops    = (const int*)d_in[1];
    const float* w_ih   = (const float*)d_in[2];
    const float* w_hh   = (const float*)d_in[3];
    const float* b_ih   = (const float*)d_in[4];
    const float* b_hh   = (const float*)d_in[5];
    float* out = (float*)d_out;

    // slots never reached by pos+1 must be zero (harness poisons with 0xAA)
    hipMemsetAsync(d_out, 0, (size_t)out_size * sizeof(float), stream);

    stack_lstm_kernel<<<dim3(BATCH), dim3(1024), 0, stream>>>(
        inputs, ops, w_ih, w_hh, b_ih, b_hh, out);
}